// Round 11
// baseline (422.792 us; speedup 1.0000x reference)
//
#include <hip/hip_runtime.h>
#include <hip/hip_bf16.h>
#include <stdint.h>
#include <stddef.h>

typedef __attribute__((ext_vector_type(8))) short bf16x8;
typedef __attribute__((ext_vector_type(4))) float f32x4;

typedef __attribute__((address_space(1))) const unsigned int g_as1;
typedef __attribute__((address_space(3))) unsigned int lds_as3;
__device__ __forceinline__ void gload_lds16(const void* g, void* l) {
  __builtin_amdgcn_global_load_lds((g_as1*)g, (lds_as3*)l, 16, 0, 0);
}

__device__ __forceinline__ unsigned short f2bf(float f) {
  union { float f; unsigned int u; } v; v.f = f;
  unsigned int u = v.u;
  u += 0x7fffu + ((u >> 16) & 1u);   // round-to-nearest-even
  return (unsigned short)(u >> 16);
}
__device__ __forceinline__ float bf2f(unsigned short s) {
  union { unsigned int u; float f; } v; v.u = ((unsigned int)s) << 16;
  return v.f;
}
// packed f32x2 -> bf16x2 (RTNE) via vendor intrinsic (hand asm NaN'd — r4).
__device__ __forceinline__ unsigned cvt_pk_bf16(float lo, float hi) {
  __hip_bfloat162 h2 = __float22bfloat162_rn(make_float2(lo, hi));
  unsigned r;
  __builtin_memcpy(&r, &h2, 4);
  return r;
}

// Tile image layout: a (bm,kk) tile of 128 rows x 64 cols bf16 occupies 16KB;
// element (r,c) at byte  r*128 + ((c*2) ^ ((r&7)<<4)).  Equals the swizzled
// LDS image, so linear global_load_lds reproduces it in LDS.

// ---------------------------------------------------------------------------
// prep: wqkv -> tile image [bn=12][kk=8]; wproj -> tile image [bn=4][kk=8];
//       relk_b [256][64] bf16 (rows>=225 zero); relvT_b [64][256] bf16.
// ---------------------------------------------------------------------------
__global__ void prep_kernel(const float* __restrict__ wqkv,
                            const float* __restrict__ wproj,
                            const float* __restrict__ relk,
                            const float* __restrict__ relv,
                            short* __restrict__ wq_t,
                            short* __restrict__ wp_t,
                            short* __restrict__ relk_b,
                            short* __restrict__ relvT_b) {
  const int g = blockIdx.x * 256 + threadIdx.x;  // 0..135167
  if (g < 98304) {  // wqkv: 1536 rows x 64 granules
    const int row = g >> 6, c8 = g & 63;
    const float* s = wqkv + (size_t)row * 512 + c8 * 8;
    float4 f0 = *(const float4*)s;
    float4 f1 = *(const float4*)(s + 4);
    uint4 w;
    w.x = f2bf(f0.x) | ((unsigned)f2bf(f0.y) << 16);
    w.y = f2bf(f0.z) | ((unsigned)f2bf(f0.w) << 16);
    w.z = f2bf(f1.x) | ((unsigned)f2bf(f1.y) << 16);
    w.w = f2bf(f1.z) | ((unsigned)f2bf(f1.w) << 16);
    const int bn = row >> 7, rl = row & 127, kk = c8 >> 3, c8l = c8 & 7;
    char* d = (char*)wq_t + (size_t)(bn * 8 + kk) * 16384 + rl * 128 +
              ((c8l * 16) ^ ((rl & 7) << 4));
    *(uint4*)d = w;
  } else if (g < 131072) {  // wproj: 512 rows x 64 granules
    const int g2 = g - 98304;
    const int row = g2 >> 6, c8 = g2 & 63;
    const float* s = wproj + (size_t)row * 512 + c8 * 8;
    float4 f0 = *(const float4*)s;
    float4 f1 = *(const float4*)(s + 4);
    uint4 w;
    w.x = f2bf(f0.x) | ((unsigned)f2bf(f0.y) << 16);
    w.y = f2bf(f0.z) | ((unsigned)f2bf(f0.w) << 16);
    w.z = f2bf(f1.x) | ((unsigned)f2bf(f1.y) << 16);
    w.w = f2bf(f1.z) | ((unsigned)f2bf(f1.w) << 16);
    const int bn = row >> 7, rl = row & 127, kk = c8 >> 3, c8l = c8 & 7;
    char* d = (char*)wp_t + (size_t)(bn * 8 + kk) * 16384 + rl * 128 +
              ((c8l * 16) ^ ((rl & 7) << 4));
    *(uint4*)d = w;
  } else if (g < 133120) {  // relk: 256 rows x 8 granules
    const int g3 = g - 131072;
    const int nb = g3 >> 3, c8 = g3 & 7;
    uint4 w = {0u, 0u, 0u, 0u};
    if (nb < 225) {
      const float* s = relk + (size_t)nb * 64 + c8 * 8;
      float4 f0 = *(const float4*)s;
      float4 f1 = *(const float4*)(s + 4);
      w.x = f2bf(f0.x) | ((unsigned)f2bf(f0.y) << 16);
      w.y = f2bf(f0.z) | ((unsigned)f2bf(f0.w) << 16);
      w.z = f2bf(f1.x) | ((unsigned)f2bf(f1.y) << 16);
      w.w = f2bf(f1.z) | ((unsigned)f2bf(f1.w) << 16);
    }
    *(uint4*)(relk_b + nb * 64 + c8 * 8) = w;
  } else {  // relvT: 64 d-rows x 32 granules of 8 (bf16, transposed)
    const int g4 = g - 133120;
    const int d = g4 >> 5, nb0 = (g4 & 31) * 8;
    unsigned short s[8];
#pragma unroll
    for (int j = 0; j < 8; ++j) {
      const int nb = nb0 + j;
      s[j] = (nb < 225) ? f2bf(relv[(size_t)nb * 64 + d]) : (unsigned short)0;
    }
    uint4 w;
    w.x = s[0] | ((unsigned)s[1] << 16);
    w.y = s[2] | ((unsigned)s[3] << 16);
    w.z = s[4] | ((unsigned)s[5] << 16);
    w.w = s[6] | ((unsigned)s[7] << 16);
    *(uint4*)(relvT_b + d * 256 + nb0) = w;
  }
}

// ---------------------------------------------------------------------------
// xconv: x fp32 [65536][512] -> bf16 tile image [bm=512][kk=8].
// ---------------------------------------------------------------------------
__global__ void xconv_kernel(const float* __restrict__ x, short* __restrict__ x_t) {
  const int g = blockIdx.x * 256 + threadIdx.x;  // 0..4194303
  const int row = g >> 6, c8 = g & 63;
  const float* s = x + (size_t)row * 512 + c8 * 8;
  float4 f0 = *(const float4*)s;
  float4 f1 = *(const float4*)(s + 4);
  uint4 w;
  w.x = f2bf(f0.x) | ((unsigned)f2bf(f0.y) << 16);
  w.y = f2bf(f0.z) | ((unsigned)f2bf(f0.w) << 16);
  w.z = f2bf(f1.x) | ((unsigned)f2bf(f1.y) << 16);
  w.w = f2bf(f1.z) | ((unsigned)f2bf(f1.w) << 16);
  const int bm = row >> 7, rl = row & 127, kk = c8 >> 3, c8l = c8 & 7;
  char* d = (char*)x_t + (size_t)(bm * 8 + kk) * 16384 + rl * 128 +
            ((c8l * 16) ^ ((rl & 7) << 4));
  *(uint4*)d = w;
}

// ---------------------------------------------------------------------------
// QKV GEMM (m97 structure): M=65536, N=1536, K=512. A,B pre-tiled bf16.
// q/k tiles use SWAPPED mfma operands (C^T): register axis runs along d ->
// vectorized uint2 epilogue in [t][d] layout. v tiles unswapped ([d][t]).
// q epilogue pre-scales by 0.125*log2(e) so attn softmax uses bare exp2.
// ---------------------------------------------------------------------------
__global__ __launch_bounds__(256)
void qkv_gemm(const short* __restrict__ x_t, const short* __restrict__ wq_t,
              short* __restrict__ q_g, short* __restrict__ k_g,
              short* __restrict__ vT_g) {
  __shared__ __align__(16) short As[8192];  // 16KB
  __shared__ __align__(16) short Bs[8192];  // 16KB
  const int tid = threadIdx.x;
  const int lane = tid & 63;
  const int l15 = lane & 15, l4 = lane >> 4;
  const int wave = tid >> 6;
  const int wm = wave >> 1, wn = wave & 1;
  const int bid = blockIdx.x;  // 6144
  const int wg = (bid & 7) * 768 + (bid >> 3);
  const int bn = wg % 12;
  const int bm = wg / 12;
  char* as_ = (char*)As;
  char* bs_ = (char*)Bs;
  const char* abase = (const char*)x_t + (size_t)bm * 131072;
  const char* bbase = (const char*)wq_t + (size_t)bn * 131072;
  const int soff = tid * 16;
  const int three = bn >> 2;  // 0=q 1=k 2=v

  const f32x4 fz = {0.f, 0.f, 0.f, 0.f};
  f32x4 acc[4][4];
#pragma unroll
  for (int mt = 0; mt < 4; ++mt)
#pragma unroll
    for (int nt = 0; nt < 4; ++nt) acc[mt][nt] = fz;

#pragma unroll 1
  for (int kk = 0; kk < 8; ++kk) {
    const char* ga = abase + kk * 16384 + soff;
    const char* gb = bbase + kk * 16384 + soff;
#pragma unroll
    for (int i = 0; i < 4; ++i) {
      gload_lds16(ga + i * 4096, as_ + soff + i * 4096);
      gload_lds16(gb + i * 4096, bs_ + soff + i * 4096);
    }
    __syncthreads();
#pragma unroll
    for (int ki = 0; ki < 2; ++ki) {
      bf16x8 af[4], bfr[4];
#pragma unroll
      for (int mt = 0; mt < 4; ++mt) {
        const int row = 64 * wm + 16 * mt + l15;
        af[mt] = *(const bf16x8*)(as_ + row * 128 + ((64 * ki + 16 * l4) ^ ((row & 7) << 4)));
      }
#pragma unroll
      for (int nt = 0; nt < 4; ++nt) {
        const int row = 64 * wn + 16 * nt + l15;
        bfr[nt] = *(const bf16x8*)(bs_ + row * 128 + ((64 * ki + 16 * l4) ^ ((row & 7) << 4)));
      }
      if (three < 2) {  // q,k: swapped -> C^T (reg axis = d)
#pragma unroll
        for (int mt = 0; mt < 4; ++mt)
#pragma unroll
          for (int nt = 0; nt < 4; ++nt)
            acc[mt][nt] = __builtin_amdgcn_mfma_f32_16x16x32_bf16(bfr[nt], af[mt], acc[mt][nt], 0, 0, 0);
      } else {          // v: normal (reg axis = t, for [d][t] epilogue)
#pragma unroll
        for (int mt = 0; mt < 4; ++mt)
#pragma unroll
          for (int nt = 0; nt < 4; ++nt)
            acc[mt][nt] = __builtin_amdgcn_mfma_f32_16x16x32_bf16(af[mt], bfr[nt], acc[mt][nt], 0, 0, 0);
      }
    }
    __syncthreads();
  }

  if (three < 2) {
    // C^T: col(l15)=m-dir (t), row(4*l4+jj)=n-dir (d). 16 uint2 stores.
    short* dst = (three == 0) ? q_g : k_g;
    const float qsc = (three == 0) ? 0.18033688f : 1.0f;  // 0.125*log2(e) in q
    const int b = bm * 2 + wm;
    const int h = (bn & 3) * 2 + wn;
#pragma unroll
    for (int mt = 0; mt < 4; ++mt) {
      const int t = 16 * mt + l15;
      short* p = dst + (size_t)(b * 8 + h) * 4096 + t * 64;
#pragma unroll
      for (int nt = 0; nt < 4; ++nt) {
        const int d0 = 16 * nt + 4 * l4;
        uint2 w;
        w.x = cvt_pk_bf16(acc[mt][nt][0] * qsc, acc[mt][nt][1] * qsc);
        w.y = cvt_pk_bf16(acc[mt][nt][2] * qsc, acc[mt][nt][3] * qsc);
        *(uint2*)(p + d0) = w;
      }
    }
  } else {
#pragma unroll
    for (int mt = 0; mt < 4; ++mt) {
      const int m0 = bm * 128 + 64 * wm + 16 * mt + 4 * l4;
      const int b = m0 >> 6, t0 = m0 & 63;
#pragma unroll
      for (int nt = 0; nt < 4; ++nt) {
        const int n = bn * 128 + 64 * wn + 16 * nt + l15;
        const int h = (n >> 6) & 7, d = n & 63;
        uint2 w;
        w.x = cvt_pk_bf16(acc[mt][nt][0], acc[mt][nt][1]);
        w.y = cvt_pk_bf16(acc[mt][nt][2], acc[mt][nt][3]);
        *(uint2*)(vT_g + (size_t)((b * 8 + h) * 64 + d) * 64 + t0) = w;
      }
    }
  }
}

// ---------------------------------------------------------------------------
// attention (round-10 verified, byte-identical): one block per (b,h),
// 4 waves; wave w owns rows [16w,16w+16). d-strip PV, 2 barriers, bf16 P.
// Logits arrive pre-scaled by 0.125*log2(e) -> softmax uses bare exp2.
// ---------------------------------------------------------------------------
__global__ __launch_bounds__(256, 4)
void attn_kernel(const short* __restrict__ q_g, const short* __restrict__ k_g,
                 const short* __restrict__ vT_g, const short* __restrict__ relk,
                 const short* __restrict__ relvT, short* __restrict__ aout_t) {
  __shared__ __align__(16) short srel_s[64 * 256];  // 32KB swizzled [i][nb]; reused as P
  __shared__ __align__(16) short attn_s[64 * 64];   // 8KB swizzled  [i][j]
  const int tid = threadIdx.x, lane = tid & 63, w = tid >> 6;
  const int l15 = lane & 15, l4 = lane >> 4;
  const int bh = blockIdx.x;
  const short* qb = q_g + (size_t)bh * 4096;
  const short* kb = k_g + (size_t)bh * 4096;
  const short* vb = vT_g + (size_t)bh * 4096;
  char* ss = (char*)srel_s;
  char* as = (char*)attn_s;
  const f32x4 fz = {0.f, 0.f, 0.f, 0.f};

  // ---- Srel^T: D[nb,i] = sum_d relk[nb,d] q[i,d]
  bf16x8 bq[4][2];
#pragma unroll
  for (int nt = 0; nt < 4; ++nt)
#pragma unroll
    for (int kkk = 0; kkk < 2; ++kkk)
      bq[nt][kkk] = *(const bf16x8*)(qb + (16 * nt + l15) * 64 + 32 * kkk + 8 * l4);
#pragma unroll
  for (int mtl = 0; mtl < 4; ++mtl) {
    const int mt = 4 * w + mtl;
    bf16x8 ar0 = *(const bf16x8*)(relk + (16 * mt + l15) * 64 + 8 * l4);
    bf16x8 ar1 = *(const bf16x8*)(relk + (16 * mt + l15) * 64 + 32 + 8 * l4);
#pragma unroll
    for (int nt = 0; nt < 4; ++nt) {
      f32x4 a = fz;
      a = __builtin_amdgcn_mfma_f32_16x16x32_bf16(ar0, bq[nt][0], a, 0, 0, 0);
      a = __builtin_amdgcn_mfma_f32_16x16x32_bf16(ar1, bq[nt][1], a, 0, 0, 0);
      const int i = 16 * nt + l15;
      const int nb0 = 16 * mt + 4 * l4;
      uint2 wv;
      wv.x = cvt_pk_bf16(a[0], a[1]);
      wv.y = cvt_pk_bf16(a[2], a[3]);
      *(uint2*)(ss + i * 512 + ((nb0 * 2) ^ ((i & 7) << 4))) = wv;
    }
  }

  // ---- S^T (own strip): D[j,i] = sum_d k[j,d] q[i,d], i = 16w+l15
  f32x4 sacc[4];
#pragma unroll
  for (int jt = 0; jt < 4; ++jt) {
    sacc[jt] = fz;
    bf16x8 ak0 = *(const bf16x8*)(kb + (16 * jt + l15) * 64 + 8 * l4);
    bf16x8 ak1 = *(const bf16x8*)(kb + (16 * jt + l15) * 64 + 32 + 8 * l4);
    sacc[jt] = __builtin_amdgcn_mfma_f32_16x16x32_bf16(ak0, bq[w][0], sacc[jt], 0, 0, 0);
    sacc[jt] = __builtin_amdgcn_mfma_f32_16x16x32_bf16(ak1, bq[w][1], sacc[jt], 0, 0, 0);
  }
  __syncthreads();  // barrier 1: Srel complete

  // ---- softmax over own rows (4 lanes per row, 16 logits each) ----
  // nb(i,j) = [15*(j>>3)+(j&7)+112] - [15*(i>>3)+(i&7)]; 2nb = 60jt+2rg+off2.
  const int i = 16 * w + l15;
  const int swz = (i & 7) << 4;
  const int ibase = i * 512;
  const int off2 = 2 * (15 * (l4 >> 1) + 4 * (l4 & 1) + 112 - (15 * (i >> 3) + (i & 7)));
  float p[16];
  float mx = -1e30f;
#pragma unroll
  for (int jt = 0; jt < 4; ++jt)
#pragma unroll
    for (int rg = 0; rg < 4; ++rg) {
      const int adr = ibase + (((60 * jt + 2 * rg) + off2) ^ swz);
      const float sr = bf2f(*(const unsigned short*)(ss + adr));
      const float lv = sacc[jt][rg] + sr;
      p[4 * jt + rg] = lv;
      mx = fmaxf(mx, lv);
    }
  mx = fmaxf(mx, __shfl_xor(mx, 16));
  mx = fmaxf(mx, __shfl_xor(mx, 32));
  float sum = 0.f;
#pragma unroll
  for (int q2 = 0; q2 < 16; ++q2) {
    p[q2] = exp2f(p[q2] - mx);   // scale pre-folded into q (qkv epilogue)
    sum += p[q2];
  }
  sum += __shfl_xor(sum, 16);
  sum += __shfl_xor(sum, 32);
  const float rs = 1.0f / sum;
  unsigned pk[8];
#pragma unroll
  for (int h2 = 0; h2 < 8; ++h2)
    pk[h2] = cvt_pk_bf16(p[2 * h2] * rs, p[2 * h2 + 1] * rs);
  // attn_s[i][j] packed
#pragma unroll
  for (int jt = 0; jt < 4; ++jt) {
    uint2 wv;
    wv.x = pk[2 * jt];
    wv.y = pk[2 * jt + 1];
    *(uint2*)(as + i * 128 + (((16 * jt + 4 * l4) * 2) ^ swz)) = wv;
  }
  {  // zero own P row quarter (gather reads above precede in program order)
    const uint4 uz = {0u, 0u, 0u, 0u};
#pragma unroll
    for (int c = 0; c < 8; ++c)
      *(uint4*)(ss + ibase + ((l4 * 128 + c * 16) ^ swz)) = uz;
  }
#pragma unroll
  for (int jt = 0; jt < 4; ++jt)  // scatter P (injective per row)
#pragma unroll
    for (int rg = 0; rg < 4; ++rg) {
      const int adr = ibase + (((60 * jt + 2 * rg) + off2) ^ swz);
      const int q2 = 4 * jt + rg;
      const unsigned v = pk[q2 >> 1] >> ((q2 & 1) * 16);
      *(unsigned short*)(ss + adr) = (unsigned short)v;
    }
  __syncthreads();  // barrier 2: attn + P visible

  // ---- PV: D[d,t] = sum_j vT[d,j]attn[t,j] + sum_nb relvT[d,nb]P[t,nb]
  f32x4 oacc[4];
#pragma unroll
  for (int nt = 0; nt < 4; ++nt) oacc[nt] = fz;
#pragma unroll
  for (int kkk = 0; kkk < 2; ++kkk) {
    bf16x8 av = *(const bf16x8*)(vb + (16 * w + l15) * 64 + 32 * kkk + 8 * l4);
#pragma unroll
    for (int nt = 0; nt < 4; ++nt) {
      const int t = 16 * nt + l15;
      bf16x8 bp = *(const bf16x8*)(as + t * 128 + (((32 * kkk + 8 * l4) * 2) ^ ((t & 7) << 4)));
      oacc[nt] = __builtin_amdgcn_mfma_f32_16x16x32_bf16(av, bp, oacc[nt], 0, 0, 0);
    }
  }
#pragma unroll
  for (int kkk = 0; kkk < 8; ++kkk) {
    bf16x8 arv = *(const bf16x8*)(relvT + (16 * w + l15) * 256 + 32 * kkk + 8 * l4);
#pragma unroll
    for (int nt = 0; nt < 4; ++nt) {
      const int t = 16 * nt + l15;
      bf16x8 bp = *(const bf16x8*)(ss + t * 512 + (((32 * kkk + 8 * l4) * 2) ^ ((t & 7) << 4)));
      oacc[nt] = __builtin_amdgcn_mfma_f32_16x16x32_bf16(arv, bp, oacc[nt], 0, 0, 0);
    }
  }

  // epilogue: write into proj tile image. row m=b*64+t; tile bm=m>>7, kk=h.
  const int b = bh >> 3, h = bh & 7;
  char* abase = (char*)aout_t + (size_t)((b >> 1) * 8 + h) * 16384;
  const int rbase = (b & 1) * 64;
#pragma unroll
  for (int nt = 0; nt < 4; ++nt) {
    const int t = 16 * nt + l15;
    const int r = rbase + t;
    const int d0 = 16 * w + 4 * l4;
    uint2 wv;
    wv.x = cvt_pk_bf16(oacc[nt][0], oacc[nt][1]);
    wv.y = cvt_pk_bf16(oacc[nt][2], oacc[nt][3]);
    *(uint2*)(abase + r * 128 + ((d0 * 2) ^ ((r & 7) << 4))) = wv;
  }
}

// ---------------------------------------------------------------------------
// proj (m97 structure, swapped mfma -> C^T): out = aout @ wproj^T + b_proj.
// Register axis = col -> float4 stores with float4 bias.
// ---------------------------------------------------------------------------
__global__ __launch_bounds__(256)
void proj_kernel(const short* __restrict__ a_t, const short* __restrict__ wp_t,
                 const float* __restrict__ bproj, float* __restrict__ out) {
  __shared__ __align__(16) short As[8192];
  __shared__ __align__(16) short Bs[8192];
  const int tid = threadIdx.x;
  const int lane = tid & 63;
  const int wave = tid >> 6;
  const int wm = wave >> 1, wn = wave & 1;
  const int l15 = lane & 15, l4 = lane >> 4;
  const int bid = blockIdx.x;  // 2048
  const int wg = (bid & 7) * 256 + (bid >> 3);
  const int bn = wg & 3;
  const int bm = wg >> 2;
  char* as_ = (char*)As;
  char* bs_ = (char*)Bs;
  const char* abase = (const char*)a_t + (size_t)bm * 131072;
  const char* bbase = (const char*)wp_t + (size_t)bn * 131072;
  const int soff = tid * 16;

  const f32x4 fz = {0.f, 0.f, 0.f, 0.f};
  f32x4 acc[4][4];
#pragma unroll
  for (int mt = 0; mt < 4; ++mt)
#pragma unroll
    for (int nt = 0; nt < 4; ++nt) acc[mt][nt] = fz;

#pragma unroll 1
  for (int kk = 0; kk < 8; ++kk) {
    const char* ga = abase + kk * 16384 + soff;
    const char* gb = bbase + kk * 16384 + soff;
#pragma unroll
    for (int i = 0; i < 4; ++i) {
      gload_lds16(ga + i * 4096, as_ + soff + i * 4096);
      gload_lds16(gb + i * 4096, bs_ + soff + i * 4096);
    }
    __syncthreads();
#pragma unroll
    for (int ki = 0; ki < 2; ++ki) {
      bf16x8 af[4], bq[4];
#pragma unroll
      for (int mt = 0; mt < 4; ++mt) {
        const int row = 64 * wm + 16 * mt + l15;
        af[mt] = *(const bf16x8*)(as_ + row * 128 + ((64 * ki + 16 * l4) ^ ((row & 7) << 4)));
      }
#pragma unroll
      for (int nt = 0; nt < 4; ++nt) {
        const int row = 64 * wn + 16 * nt + l15;
        bq[nt] = *(const bf16x8*)(bs_ + row * 128 + ((64 * ki + 16 * l4) ^ ((row & 7) << 4)));
      }
#pragma unroll
      for (int mt = 0; mt < 4; ++mt)
#pragma unroll
        for (int nt = 0; nt < 4; ++nt)
          acc[mt][nt] = __builtin_amdgcn_mfma_f32_16x16x32_bf16(bq[nt], af[mt], acc[mt][nt], 0, 0, 0);
    }
    __syncthreads();
  }
  // C^T epilogue: col(l15) = row r of out, reg axis = 4 consecutive cols.
#pragma unroll
  for (int nt = 0; nt < 4; ++nt) {
    const int col0 = bn * 128 + 64 * wn + 16 * nt + 4 * l4;
    const float4 b4 = *(const float4*)(bproj + col0);
#pragma unroll
    for (int mt = 0; mt < 4; ++mt) {
      const int r = bm * 128 + 64 * wm + 16 * mt + l15;
      float4 o;
      o.x = acc[mt][nt][0] + b4.x;
      o.y = acc[mt][nt][1] + b4.y;
      o.z = acc[mt][nt][2] + b4.z;
      o.w = acc[mt][nt][3] + b4.w;
      *(float4*)(out + (size_t)r * 512 + col0) = o;
    }
  }
}

// ---------------------------------------------------------------------------
extern "C" void kernel_launch(void* const* d_in, const int* in_sizes, int n_in,
                              void* d_out, int out_size, void* d_ws, size_t ws_size,
                              hipStream_t stream) {
  const float* x = (const float*)d_in[0];
  const float* wqkv = (const float*)d_in[1];
  const float* wproj = (const float*)d_in[2];
  const float* bproj = (const float*)d_in[3];
  const float* relk = (const float*)d_in[4];
  const float* relv = (const float*)d_in[5];
  float* out = (float*)d_out;

  char* ws = (char*)d_ws;
  const size_t MB = 1024 * 1024;
  // region A (64MB): x_t during qkv_gemm, then aout_t from attn onward
  short* xa_t = (short*)ws;
  short* vT_g = (short*)(ws + 64 * MB);                 // 64MB
  short* wq_t = (short*)(ws + 128 * MB);                // 1.5MB
  short* wp_t = (short*)(ws + 128 * MB + 1572864);      // 0.5MB
  short* relk_b = (short*)(ws + 128 * MB + 2097152);    // 32KB
  short* relvT_b = (short*)(ws + 128 * MB + 2129920);   // 32KB
  short* q_gg = (short*)d_out;                          // parked in d_out
  short* k_gg = (short*)((char*)d_out + 64 * MB);       // until proj overwrites

  prep_kernel<<<dim3(528), dim3(256), 0, stream>>>(wqkv, wproj, relk, relv, wq_t,
                                                   wp_t, relk_b, relvT_b);
  xconv_kernel<<<dim3(16384), dim3(256), 0, stream>>>(x, xa_t);
  qkv_gemm<<<dim3(6144), dim3(256), 0, stream>>>(xa_t, wq_t, q_gg, k_gg, vT_g);
  attn_kernel<<<dim3(8192), dim3(256), 0, stream>>>(q_gg, k_gg, vT_g, relk_b,
                                                    relvT_b, xa_t);
  proj_kernel<<<dim3(2048), dim3(256), 0, stream>>>(xa_t, wp_t, bproj, out);
}

// Round 12
// 376.211 us; speedup vs baseline: 1.1238x; 1.1238x over previous
//
#include <hip/hip_runtime.h>
#include <hip/hip_bf16.h>
#include <stdint.h>
#include <stddef.h>

typedef __attribute__((ext_vector_type(8))) short bf16x8;
typedef __attribute__((ext_vector_type(4))) float f32x4;

typedef __attribute__((address_space(1))) const unsigned int g_as1;
typedef __attribute__((address_space(3))) unsigned int lds_as3;
__device__ __forceinline__ void gload_lds16(const void* g, void* l) {
  __builtin_amdgcn_global_load_lds((g_as1*)g, (lds_as3*)l, 16, 0, 0);
}

__device__ __forceinline__ unsigned short f2bf(float f) {
  union { float f; unsigned int u; } v; v.f = f;
  unsigned int u = v.u;
  u += 0x7fffu + ((u >> 16) & 1u);   // round-to-nearest-even
  return (unsigned short)(u >> 16);
}
__device__ __forceinline__ float bf2f(unsigned short s) {
  union { unsigned int u; float f; } v; v.u = ((unsigned int)s) << 16;
  return v.f;
}
// packed f32x2 -> bf16x2 (RTNE) via vendor intrinsic (hand asm NaN'd — r4).
__device__ __forceinline__ unsigned cvt_pk_bf16(float lo, float hi) {
  __hip_bfloat162 h2 = __float22bfloat162_rn(make_float2(lo, hi));
  unsigned r;
  __builtin_memcpy(&r, &h2, 4);
  return r;
}

// Tile image layout: a (bm,kk) tile of 128 rows x 64 cols bf16 occupies 16KB;
// element (r,c) at byte  r*128 + ((c*2) ^ ((r&7)<<4)).  Equals the swizzled
// LDS image, so linear global_load_lds reproduces it in LDS.

// ---------------------------------------------------------------------------
// prep: wqkv -> tile image [bn=12][kk=8]; wproj -> tile image [bn=4][kk=8];
//       relk_b [256][64] bf16 (rows>=225 zero); relvT_b [64][256] bf16.
// ---------------------------------------------------------------------------
__global__ void prep_kernel(const float* __restrict__ wqkv,
                            const float* __restrict__ wproj,
                            const float* __restrict__ relk,
                            const float* __restrict__ relv,
                            short* __restrict__ wq_t,
                            short* __restrict__ wp_t,
                            short* __restrict__ relk_b,
                            short* __restrict__ relvT_b) {
  const int g = blockIdx.x * 256 + threadIdx.x;  // 0..135167
  if (g < 98304) {  // wqkv: 1536 rows x 64 granules
    const int row = g >> 6, c8 = g & 63;
    const float* s = wqkv + (size_t)row * 512 + c8 * 8;
    float4 f0 = *(const float4*)s;
    float4 f1 = *(const float4*)(s + 4);
    uint4 w;
    w.x = f2bf(f0.x) | ((unsigned)f2bf(f0.y) << 16);
    w.y = f2bf(f0.z) | ((unsigned)f2bf(f0.w) << 16);
    w.z = f2bf(f1.x) | ((unsigned)f2bf(f1.y) << 16);
    w.w = f2bf(f1.z) | ((unsigned)f2bf(f1.w) << 16);
    const int bn = row >> 7, rl = row & 127, kk = c8 >> 3, c8l = c8 & 7;
    char* d = (char*)wq_t + (size_t)(bn * 8 + kk) * 16384 + rl * 128 +
              ((c8l * 16) ^ ((rl & 7) << 4));
    *(uint4*)d = w;
  } else if (g < 131072) {  // wproj: 512 rows x 64 granules
    const int g2 = g - 98304;
    const int row = g2 >> 6, c8 = g2 & 63;
    const float* s = wproj + (size_t)row * 512 + c8 * 8;
    float4 f0 = *(const float4*)s;
    float4 f1 = *(const float4*)(s + 4);
    uint4 w;
    w.x = f2bf(f0.x) | ((unsigned)f2bf(f0.y) << 16);
    w.y = f2bf(f0.z) | ((unsigned)f2bf(f0.w) << 16);
    w.z = f2bf(f1.x) | ((unsigned)f2bf(f1.y) << 16);
    w.w = f2bf(f1.z) | ((unsigned)f2bf(f1.w) << 16);
    const int bn = row >> 7, rl = row & 127, kk = c8 >> 3, c8l = c8 & 7;
    char* d = (char*)wp_t + (size_t)(bn * 8 + kk) * 16384 + rl * 128 +
              ((c8l * 16) ^ ((rl & 7) << 4));
    *(uint4*)d = w;
  } else if (g < 133120) {  // relk: 256 rows x 8 granules
    const int g3 = g - 131072;
    const int nb = g3 >> 3, c8 = g3 & 7;
    uint4 w = {0u, 0u, 0u, 0u};
    if (nb < 225) {
      const float* s = relk + (size_t)nb * 64 + c8 * 8;
      float4 f0 = *(const float4*)s;
      float4 f1 = *(const float4*)(s + 4);
      w.x = f2bf(f0.x) | ((unsigned)f2bf(f0.y) << 16);
      w.y = f2bf(f0.z) | ((unsigned)f2bf(f0.w) << 16);
      w.z = f2bf(f1.x) | ((unsigned)f2bf(f1.y) << 16);
      w.w = f2bf(f1.z) | ((unsigned)f2bf(f1.w) << 16);
    }
    *(uint4*)(relk_b + nb * 64 + c8 * 8) = w;
  } else {  // relvT: 64 d-rows x 32 granules of 8 (bf16, transposed)
    const int g4 = g - 133120;
    const int d = g4 >> 5, nb0 = (g4 & 31) * 8;
    unsigned short s[8];
#pragma unroll
    for (int j = 0; j < 8; ++j) {
      const int nb = nb0 + j;
      s[j] = (nb < 225) ? f2bf(relv[(size_t)nb * 64 + d]) : (unsigned short)0;
    }
    uint4 w;
    w.x = s[0] | ((unsigned)s[1] << 16);
    w.y = s[2] | ((unsigned)s[3] << 16);
    w.z = s[4] | ((unsigned)s[5] << 16);
    w.w = s[6] | ((unsigned)s[7] << 16);
    *(uint4*)(relvT_b + d * 256 + nb0) = w;
  }
}

// ---------------------------------------------------------------------------
// xconv: x fp32 [65536][512] -> bf16 tile image [bm=512][kk=8].
// ---------------------------------------------------------------------------
__global__ void xconv_kernel(const float* __restrict__ x, short* __restrict__ x_t) {
  const int g = blockIdx.x * 256 + threadIdx.x;  // 0..4194303
  const int row = g >> 6, c8 = g & 63;
  const float* s = x + (size_t)row * 512 + c8 * 8;
  float4 f0 = *(const float4*)s;
  float4 f1 = *(const float4*)(s + 4);
  uint4 w;
  w.x = f2bf(f0.x) | ((unsigned)f2bf(f0.y) << 16);
  w.y = f2bf(f0.z) | ((unsigned)f2bf(f0.w) << 16);
  w.z = f2bf(f1.x) | ((unsigned)f2bf(f1.y) << 16);
  w.w = f2bf(f1.z) | ((unsigned)f2bf(f1.w) << 16);
  const int bm = row >> 7, rl = row & 127, kk = c8 >> 3, c8l = c8 & 7;
  char* d = (char*)x_t + (size_t)(bm * 8 + kk) * 16384 + rl * 128 +
            ((c8l * 16) ^ ((rl & 7) << 4));
  *(uint4*)d = w;
}

// ---------------------------------------------------------------------------
// QKV GEMM (m97 structure): M=65536, N=1536, K=512. A,B pre-tiled bf16.
// ---------------------------------------------------------------------------
__global__ __launch_bounds__(256)
void qkv_gemm(const short* __restrict__ x_t, const short* __restrict__ wq_t,
              short* __restrict__ q_g, short* __restrict__ k_g,
              short* __restrict__ vT_g) {
  __shared__ __align__(16) short As[8192];  // 16KB
  __shared__ __align__(16) short Bs[8192];  // 16KB
  const int tid = threadIdx.x;
  const int lane = tid & 63;
  const int l15 = lane & 15, l4 = lane >> 4;
  const int wave = tid >> 6;
  const int wm = wave >> 1, wn = wave & 1;
  const int bid = blockIdx.x;  // 6144
  const int wg = (bid & 7) * 768 + (bid >> 3);
  const int bn = wg % 12;
  const int bm = wg / 12;
  char* as_ = (char*)As;
  char* bs_ = (char*)Bs;
  const char* abase = (const char*)x_t + (size_t)bm * 131072;
  const char* bbase = (const char*)wq_t + (size_t)bn * 131072;
  const int soff = tid * 16;

  const f32x4 fz = {0.f, 0.f, 0.f, 0.f};
  f32x4 acc[4][4];
#pragma unroll
  for (int mt = 0; mt < 4; ++mt)
#pragma unroll
    for (int nt = 0; nt < 4; ++nt) acc[mt][nt] = fz;

#pragma unroll 1
  for (int kk = 0; kk < 8; ++kk) {
    const char* ga = abase + kk * 16384 + soff;
    const char* gb = bbase + kk * 16384 + soff;
#pragma unroll
    for (int i = 0; i < 4; ++i) {
      gload_lds16(ga + i * 4096, as_ + soff + i * 4096);
      gload_lds16(gb + i * 4096, bs_ + soff + i * 4096);
    }
    __syncthreads();
#pragma unroll
    for (int ki = 0; ki < 2; ++ki) {
      bf16x8 af[4], bfr[4];
#pragma unroll
      for (int mt = 0; mt < 4; ++mt) {
        const int row = 64 * wm + 16 * mt + l15;
        af[mt] = *(const bf16x8*)(as_ + row * 128 + ((64 * ki + 16 * l4) ^ ((row & 7) << 4)));
      }
#pragma unroll
      for (int nt = 0; nt < 4; ++nt) {
        const int row = 64 * wn + 16 * nt + l15;
        bfr[nt] = *(const bf16x8*)(bs_ + row * 128 + ((64 * ki + 16 * l4) ^ ((row & 7) << 4)));
      }
#pragma unroll
      for (int mt = 0; mt < 4; ++mt)
#pragma unroll
        for (int nt = 0; nt < 4; ++nt)
          acc[mt][nt] = __builtin_amdgcn_mfma_f32_16x16x32_bf16(af[mt], bfr[nt], acc[mt][nt], 0, 0, 0);
    }
    __syncthreads();
  }

  const int three = bn >> 2;  // 0=q 1=k 2=v
  if (three < 2) {
    short* dst = (three == 0) ? q_g : k_g;
#pragma unroll
    for (int mt = 0; mt < 4; ++mt) {
      const int m0 = bm * 128 + 64 * wm + 16 * mt + 4 * l4;
      const int b = m0 >> 6, t0 = m0 & 63;
#pragma unroll
      for (int nt = 0; nt < 4; ++nt) {
        const int n = bn * 128 + 64 * wn + 16 * nt + l15;
        const int h = (n >> 6) & 7, d = n & 63;
        short* p = dst + (size_t)(b * 8 + h) * 4096 + d;
#pragma unroll
        for (int jj = 0; jj < 4; ++jj)
          p[(t0 + jj) * 64] = (short)f2bf(acc[mt][nt][jj]);
      }
    }
  } else {
#pragma unroll
    for (int mt = 0; mt < 4; ++mt) {
      const int m0 = bm * 128 + 64 * wm + 16 * mt + 4 * l4;
      const int b = m0 >> 6, t0 = m0 & 63;
#pragma unroll
      for (int nt = 0; nt < 4; ++nt) {
        const int n = bn * 128 + 64 * wn + 16 * nt + l15;
        const int h = (n >> 6) & 7, d = n & 63;
        uint2 w;
        w.x = cvt_pk_bf16(acc[mt][nt][0], acc[mt][nt][1]);
        w.y = cvt_pk_bf16(acc[mt][nt][2], acc[mt][nt][3]);
        *(uint2*)(vT_g + (size_t)((b * 8 + h) * 64 + d) * 64 + t0) = w;
      }
    }
  }
}

// ---------------------------------------------------------------------------
// attention: one block per (b,h), 4 waves; wave w owns rows [16w,16w+16).
// VALU-lean: packed bf16 converts, algebraic nb (= Cj - disp_i), folded scale.
// ---------------------------------------------------------------------------
__global__ __launch_bounds__(256, 4)
void attn_kernel(const short* __restrict__ q_g, const short* __restrict__ k_g,
                 const short* __restrict__ vT_g, const short* __restrict__ relk,
                 const short* __restrict__ relvT, short* __restrict__ aout_t) {
  __shared__ __align__(16) short srel_s[64 * 256];  // 32KB swizzled [i][nb]; reused as P
  __shared__ __align__(16) short attn_s[64 * 64];   // 8KB swizzled  [i][j]
  const int tid = threadIdx.x, lane = tid & 63, w = tid >> 6;
  const int l15 = lane & 15, l4 = lane >> 4;
  const int bh = blockIdx.x;
  const short* qb = q_g + (size_t)bh * 4096;
  const short* kb = k_g + (size_t)bh * 4096;
  const short* vb = vT_g + (size_t)bh * 4096;
  char* ss = (char*)srel_s;
  char* as = (char*)attn_s;
  const f32x4 fz = {0.f, 0.f, 0.f, 0.f};

  // ---- Srel^T: D[nb,i] = sum_d relk[nb,d] q[i,d]
  bf16x8 bq[4][2];
#pragma unroll
  for (int nt = 0; nt < 4; ++nt)
#pragma unroll
    for (int kkk = 0; kkk < 2; ++kkk)
      bq[nt][kkk] = *(const bf16x8*)(qb + (16 * nt + l15) * 64 + 32 * kkk + 8 * l4);
#pragma unroll
  for (int mtl = 0; mtl < 4; ++mtl) {
    const int mt = 4 * w + mtl;
    bf16x8 ar0 = *(const bf16x8*)(relk + (16 * mt + l15) * 64 + 8 * l4);
    bf16x8 ar1 = *(const bf16x8*)(relk + (16 * mt + l15) * 64 + 32 + 8 * l4);
#pragma unroll
    for (int nt = 0; nt < 4; ++nt) {
      f32x4 a = fz;
      a = __builtin_amdgcn_mfma_f32_16x16x32_bf16(ar0, bq[nt][0], a, 0, 0, 0);
      a = __builtin_amdgcn_mfma_f32_16x16x32_bf16(ar1, bq[nt][1], a, 0, 0, 0);
      const int i = 16 * nt + l15;
      const int nb0 = 16 * mt + 4 * l4;
      uint2 wv;
      wv.x = cvt_pk_bf16(a[0], a[1]);
      wv.y = cvt_pk_bf16(a[2], a[3]);
      *(uint2*)(ss + i * 512 + ((nb0 * 2) ^ ((i & 7) << 4))) = wv;
    }
  }

  // ---- S^T (own strip): D[j,i] = sum_d k[j,d] q[i,d], i = 16w+l15
  f32x4 sacc[4];
#pragma unroll
  for (int jt = 0; jt < 4; ++jt) {
    sacc[jt] = fz;
    bf16x8 ak0 = *(const bf16x8*)(kb + (16 * jt + l15) * 64 + 8 * l4);
    bf16x8 ak1 = *(const bf16x8*)(kb + (16 * jt + l15) * 64 + 32 + 8 * l4);
    sacc[jt] = __builtin_amdgcn_mfma_f32_16x16x32_bf16(ak0, bq[w][0], sacc[jt], 0, 0, 0);
    sacc[jt] = __builtin_amdgcn_mfma_f32_16x16x32_bf16(ak1, bq[w][1], sacc[jt], 0, 0, 0);
  }
  __syncthreads();  // barrier 1: Srel complete

  // ---- softmax over own rows (4 lanes per row, 16 logits each) ----
  // nb(i,j) = [15*(j>>3)+(j&7)+112] - [15*(i>>3)+(i&7)]; 2nb = 60jt+2rg+off2.
  const int i = 16 * w + l15;
  const int swz = (i & 7) << 4;
  const int ibase = i * 512;
  const int off2 = 2 * (15 * (l4 >> 1) + 4 * (l4 & 1) + 112 - (15 * (i >> 3) + (i & 7)));
  float p[16];
  float mx = -1e30f;
#pragma unroll
  for (int jt = 0; jt < 4; ++jt)
#pragma unroll
    for (int rg = 0; rg < 4; ++rg) {
      const int adr = ibase + (((60 * jt + 2 * rg) + off2) ^ swz);
      const float sr = bf2f(*(const unsigned short*)(ss + adr));
      const float lv = sacc[jt][rg] + sr;
      p[4 * jt + rg] = lv;
      mx = fmaxf(mx, lv);
    }
  mx = fmaxf(mx, __shfl_xor(mx, 16));
  mx = fmaxf(mx, __shfl_xor(mx, 32));
  float sum = 0.f;
#pragma unroll
  for (int q2 = 0; q2 < 16; ++q2) {
    p[q2] = __expf((p[q2] - mx) * 0.125f);
    sum += p[q2];
  }
  sum += __shfl_xor(sum, 16);
  sum += __shfl_xor(sum, 32);
  const float rs = 1.0f / sum;
  unsigned pk[8];
#pragma unroll
  for (int h2 = 0; h2 < 8; ++h2)
    pk[h2] = cvt_pk_bf16(p[2 * h2] * rs, p[2 * h2 + 1] * rs);
  // attn_s[i][j] packed
#pragma unroll
  for (int jt = 0; jt < 4; ++jt) {
    uint2 wv;
    wv.x = pk[2 * jt];
    wv.y = pk[2 * jt + 1];
    *(uint2*)(as + i * 128 + (((16 * jt + 4 * l4) * 2) ^ swz)) = wv;
  }
  {  // zero own P row quarter (gather reads above precede in program order)
    const uint4 uz = {0u, 0u, 0u, 0u};
#pragma unroll
    for (int c = 0; c < 8; ++c)
      *(uint4*)(ss + ibase + ((l4 * 128 + c * 16) ^ swz)) = uz;
  }
#pragma unroll
  for (int jt = 0; jt < 4; ++jt)  // scatter P (injective per row)
#pragma unroll
    for (int rg = 0; rg < 4; ++rg) {
      const int adr = ibase + (((60 * jt + 2 * rg) + off2) ^ swz);
      const int q2 = 4 * jt + rg;
      const unsigned v = pk[q2 >> 1] >> ((q2 & 1) * 16);
      *(unsigned short*)(ss + adr) = (unsigned short)v;
    }
  __syncthreads();  // barrier 2

  // ---- PV: D[d,t] = sum_j vT[d,j]attn[t,j] + sum_nb relvT[d,nb]P[t,nb]
  f32x4 oacc[4];
#pragma unroll
  for (int nt = 0; nt < 4; ++nt) oacc[nt] = fz;
#pragma unroll
  for (int kkk = 0; kkk < 2; ++kkk) {
    bf16x8 av = *(const bf16x8*)(vb + (16 * w + l15) * 64 + 32 * kkk + 8 * l4);
#pragma unroll
    for (int nt = 0; nt < 4; ++nt) {
      const int t = 16 * nt + l15;
      bf16x8 bp = *(const bf16x8*)(as + t * 128 + (((32 * kkk + 8 * l4) * 2) ^ ((t & 7) << 4)));
      oacc[nt] = __builtin_amdgcn_mfma_f32_16x16x32_bf16(av, bp, oacc[nt], 0, 0, 0);
    }
  }
#pragma unroll
  for (int kkk = 0; kkk < 8; ++kkk) {
    bf16x8 arv = *(const bf16x8*)(relvT + (16 * w + l15) * 256 + 32 * kkk + 8 * l4);
#pragma unroll
    for (int nt = 0; nt < 4; ++nt) {
      const int t = 16 * nt + l15;
      bf16x8 bp = *(const bf16x8*)(ss + t * 512 + (((32 * kkk + 8 * l4) * 2) ^ ((t & 7) << 4)));
      oacc[nt] = __builtin_amdgcn_mfma_f32_16x16x32_bf16(arv, bp, oacc[nt], 0, 0, 0);
    }
  }
  // epilogue: write into proj tile image. row m = b*64+t; tile bm=m>>7,
  // kk = h; in-tile r = (b&1)*64 + t, c = d.
  const int b = bh >> 3, h = bh & 7;
  char* abase = (char*)aout_t + (size_t)((b >> 1) * 8 + h) * 16384;
  const int rbase = (b & 1) * 64;
#pragma unroll
  for (int nt = 0; nt < 4; ++nt) {
    const int t = 16 * nt + l15;
    const int r = rbase + t;
    const int d0 = 16 * w + 4 * l4;
    uint2 wv;
    wv.x = cvt_pk_bf16(oacc[nt][0], oacc[nt][1]);
    wv.y = cvt_pk_bf16(oacc[nt][2], oacc[nt][3]);
    *(uint2*)(abase + r * 128 + ((d0 * 2) ^ ((r & 7) << 4))) = wv;
  }
}

// ---------------------------------------------------------------------------
// proj (m97 structure): out = aout(bf16,tiled) @ wproj^T(tiled) + b_proj.
// ---------------------------------------------------------------------------
__global__ __launch_bounds__(256)
void proj_kernel(const short* __restrict__ a_t, const short* __restrict__ wp_t,
                 const float* __restrict__ bproj, float* __restrict__ out) {
  __shared__ __align__(16) short As[8192];
  __shared__ __align__(16) short Bs[8192];
  const int tid = threadIdx.x;
  const int lane = tid & 63;
  const int wave = tid >> 6;
  const int wm = wave >> 1, wn = wave & 1;
  const int l15 = lane & 15, l4 = lane >> 4;
  const int bid = blockIdx.x;  // 2048
  const int wg = (bid & 7) * 256 + (bid >> 3);
  const int bn = wg & 3;
  const int bm = wg >> 2;
  char* as_ = (char*)As;
  char* bs_ = (char*)Bs;
  const char* abase = (const char*)a_t + (size_t)bm * 131072;
  const char* bbase = (const char*)wp_t + (size_t)bn * 131072;
  const int soff = tid * 16;

  const f32x4 fz = {0.f, 0.f, 0.f, 0.f};
  f32x4 acc[4][4];
#pragma unroll
  for (int mt = 0; mt < 4; ++mt)
#pragma unroll
    for (int nt = 0; nt < 4; ++nt) acc[mt][nt] = fz;

#pragma unroll 1
  for (int kk = 0; kk < 8; ++kk) {
    const char* ga = abase + kk * 16384 + soff;
    const char* gb = bbase + kk * 16384 + soff;
#pragma unroll
    for (int i = 0; i < 4; ++i) {
      gload_lds16(ga + i * 4096, as_ + soff + i * 4096);
      gload_lds16(gb + i * 4096, bs_ + soff + i * 4096);
    }
    __syncthreads();
#pragma unroll
    for (int ki = 0; ki < 2; ++ki) {
      bf16x8 af[4], bq[4];
#pragma unroll
      for (int mt = 0; mt < 4; ++mt) {
        const int row = 64 * wm + 16 * mt + l15;
        af[mt] = *(const bf16x8*)(as_ + row * 128 + ((64 * ki + 16 * l4) ^ ((row & 7) << 4)));
      }
#pragma unroll
      for (int nt = 0; nt < 4; ++nt) {
        const int row = 64 * wn + 16 * nt + l15;
        bq[nt] = *(const bf16x8*)(bs_ + row * 128 + ((64 * ki + 16 * l4) ^ ((row & 7) << 4)));
      }
#pragma unroll
      for (int mt = 0; mt < 4; ++mt)
#pragma unroll
        for (int nt = 0; nt < 4; ++nt)
          acc[mt][nt] = __builtin_amdgcn_mfma_f32_16x16x32_bf16(af[mt], bq[nt], acc[mt][nt], 0, 0, 0);
    }
    __syncthreads();
  }
#pragma unroll
  for (int nt = 0; nt < 4; ++nt) {
    const int col = bn * 128 + 64 * wn + 16 * nt + l15;
    const float bias = bproj[col];
#pragma unroll
    for (int mt = 0; mt < 4; ++mt) {
      const int r0 = bm * 128 + 64 * wm + 16 * mt + 4 * l4;
#pragma unroll
      for (int jj = 0; jj < 4; ++jj)
        out[(size_t)(r0 + jj) * 512 + col] = acc[mt][nt][jj] + bias;
    }
  }
}

// ---------------------------------------------------------------------------
extern "C" void kernel_launch(void* const* d_in, const int* in_sizes, int n_in,
                              void* d_out, int out_size, void* d_ws, size_t ws_size,
                              hipStream_t stream) {
  const float* x = (const float*)d_in[0];
  const float* wqkv = (const float*)d_in[1];
  const float* wproj = (const float*)d_in[2];
  const float* bproj = (const float*)d_in[3];
  const float* relk = (const float*)d_in[4];
  const float* relv = (const float*)d_in[5];
  float* out = (float*)d_out;

  char* ws = (char*)d_ws;
  const size_t MB = 1024 * 1024;
  // region A (64MB): x_t during qkv_gemm, then aout_t from attn onward
  short* xa_t = (short*)ws;
  short* vT_g = (short*)(ws + 64 * MB);                 // 64MB
  short* wq_t = (short*)(ws + 128 * MB);                // 1.5MB
  short* wp_t = (short*)(ws + 128 * MB + 1572864);      // 0.5MB
  short* relk_b = (short*)(ws + 128 * MB + 2097152);    // 32KB
  short* relvT_b = (short*)(ws + 128 * MB + 2129920);   // 32KB
  short* q_gg = (short*)d_out;                          // parked in d_out
  short* k_gg = (short*)((char*)d_out + 64 * MB);       // until proj overwrites

  prep_kernel<<<dim3(528), dim3(256), 0, stream>>>(wqkv, wproj, relk, relv, wq_t,
                                                   wp_t, relk_b, relvT_b);
  xconv_kernel<<<dim3(16384), dim3(256), 0, stream>>>(x, xa_t);
  qkv_gemm<<<dim3(6144), dim3(256), 0, stream>>>(xa_t, wq_t, q_gg, k_gg, vT_g);
  attn_kernel<<<dim3(8192), dim3(256), 0, stream>>>(q_gg, k_gg, vT_g, relk_b,
                                                    relvT_b, xa_t);
  proj_kernel<<<dim3(2048), dim3(256), 0, stream>>>(xa_t, wp_t, bproj, out);
}

// Round 13
// 375.907 us; speedup vs baseline: 1.1247x; 1.0008x over previous
//
#include <hip/hip_runtime.h>
#include <hip/hip_bf16.h>
#include <stdint.h>
#include <stddef.h>

typedef __attribute__((ext_vector_type(8))) short bf16x8;
typedef __attribute__((ext_vector_type(4))) float f32x4;

typedef __attribute__((address_space(1))) const unsigned int g_as1;
typedef __attribute__((address_space(3))) unsigned int lds_as3;
__device__ __forceinline__ void gload_lds16(const void* g, void* l) {
  __builtin_amdgcn_global_load_lds((g_as1*)g, (lds_as3*)l, 16, 0, 0);
}

__device__ __forceinline__ unsigned short f2bf(float f) {
  union { float f; unsigned int u; } v; v.f = f;
  unsigned int u = v.u;
  u += 0x7fffu + ((u >> 16) & 1u);   // round-to-nearest-even
  return (unsigned short)(u >> 16);
}
__device__ __forceinline__ float bf2f(unsigned short s) {
  union { unsigned int u; float f; } v; v.u = ((unsigned int)s) << 16;
  return v.f;
}
// packed f32x2 -> bf16x2 (RTNE) via vendor intrinsic (hand asm NaN'd — r4).
__device__ __forceinline__ unsigned cvt_pk_bf16(float lo, float hi) {
  __hip_bfloat162 h2 = __float22bfloat162_rn(make_float2(lo, hi));
  unsigned r;
  __builtin_memcpy(&r, &h2, 4);
  return r;
}

// Tile image layout: a (bm,kk) tile of 128 rows x 64 cols bf16 occupies 16KB;
// element (r,c) at byte  r*128 + ((c*2) ^ ((r&7)<<4)).  Equals the swizzled
// LDS image, so linear global_load_lds reproduces it in LDS.

// ---------------------------------------------------------------------------
// prep: wqkv -> tile image [bn=12][kk=8]; wproj -> tile image [bn=4][kk=8];
//       relk_b [256][64] bf16 (rows>=225 zero); relvT_b [64][256] bf16.
// ---------------------------------------------------------------------------
__global__ void prep_kernel(const float* __restrict__ wqkv,
                            const float* __restrict__ wproj,
                            const float* __restrict__ relk,
                            const float* __restrict__ relv,
                            short* __restrict__ wq_t,
                            short* __restrict__ wp_t,
                            short* __restrict__ relk_b,
                            short* __restrict__ relvT_b) {
  const int g = blockIdx.x * 256 + threadIdx.x;  // 0..135167
  if (g < 98304) {  // wqkv: 1536 rows x 64 granules
    const int row = g >> 6, c8 = g & 63;
    const float* s = wqkv + (size_t)row * 512 + c8 * 8;
    float4 f0 = *(const float4*)s;
    float4 f1 = *(const float4*)(s + 4);
    uint4 w;
    w.x = f2bf(f0.x) | ((unsigned)f2bf(f0.y) << 16);
    w.y = f2bf(f0.z) | ((unsigned)f2bf(f0.w) << 16);
    w.z = f2bf(f1.x) | ((unsigned)f2bf(f1.y) << 16);
    w.w = f2bf(f1.z) | ((unsigned)f2bf(f1.w) << 16);
    const int bn = row >> 7, rl = row & 127, kk = c8 >> 3, c8l = c8 & 7;
    char* d = (char*)wq_t + (size_t)(bn * 8 + kk) * 16384 + rl * 128 +
              ((c8l * 16) ^ ((rl & 7) << 4));
    *(uint4*)d = w;
  } else if (g < 131072) {  // wproj: 512 rows x 64 granules
    const int g2 = g - 98304;
    const int row = g2 >> 6, c8 = g2 & 63;
    const float* s = wproj + (size_t)row * 512 + c8 * 8;
    float4 f0 = *(const float4*)s;
    float4 f1 = *(const float4*)(s + 4);
    uint4 w;
    w.x = f2bf(f0.x) | ((unsigned)f2bf(f0.y) << 16);
    w.y = f2bf(f0.z) | ((unsigned)f2bf(f0.w) << 16);
    w.z = f2bf(f1.x) | ((unsigned)f2bf(f1.y) << 16);
    w.w = f2bf(f1.z) | ((unsigned)f2bf(f1.w) << 16);
    const int bn = row >> 7, rl = row & 127, kk = c8 >> 3, c8l = c8 & 7;
    char* d = (char*)wp_t + (size_t)(bn * 8 + kk) * 16384 + rl * 128 +
              ((c8l * 16) ^ ((rl & 7) << 4));
    *(uint4*)d = w;
  } else if (g < 133120) {  // relk: 256 rows x 8 granules
    const int g3 = g - 131072;
    const int nb = g3 >> 3, c8 = g3 & 7;
    uint4 w = {0u, 0u, 0u, 0u};
    if (nb < 225) {
      const float* s = relk + (size_t)nb * 64 + c8 * 8;
      float4 f0 = *(const float4*)s;
      float4 f1 = *(const float4*)(s + 4);
      w.x = f2bf(f0.x) | ((unsigned)f2bf(f0.y) << 16);
      w.y = f2bf(f0.z) | ((unsigned)f2bf(f0.w) << 16);
      w.z = f2bf(f1.x) | ((unsigned)f2bf(f1.y) << 16);
      w.w = f2bf(f1.z) | ((unsigned)f2bf(f1.w) << 16);
    }
    *(uint4*)(relk_b + nb * 64 + c8 * 8) = w;
  } else {  // relvT: 64 d-rows x 32 granules of 8 (bf16, transposed)
    const int g4 = g - 133120;
    const int d = g4 >> 5, nb0 = (g4 & 31) * 8;
    unsigned short s[8];
#pragma unroll
    for (int j = 0; j < 8; ++j) {
      const int nb = nb0 + j;
      s[j] = (nb < 225) ? f2bf(relv[(size_t)nb * 64 + d]) : (unsigned short)0;
    }
    uint4 w;
    w.x = s[0] | ((unsigned)s[1] << 16);
    w.y = s[2] | ((unsigned)s[3] << 16);
    w.z = s[4] | ((unsigned)s[5] << 16);
    w.w = s[6] | ((unsigned)s[7] << 16);
    *(uint4*)(relvT_b + d * 256 + nb0) = w;
  }
}

// ---------------------------------------------------------------------------
// xconv: x fp32 [65536][512] -> bf16 tile image [bm=512][kk=8].
// ---------------------------------------------------------------------------
__global__ void xconv_kernel(const float* __restrict__ x, short* __restrict__ x_t) {
  const int g = blockIdx.x * 256 + threadIdx.x;  // 0..4194303
  const int row = g >> 6, c8 = g & 63;
  const float* s = x + (size_t)row * 512 + c8 * 8;
  float4 f0 = *(const float4*)s;
  float4 f1 = *(const float4*)(s + 4);
  uint4 w;
  w.x = f2bf(f0.x) | ((unsigned)f2bf(f0.y) << 16);
  w.y = f2bf(f0.z) | ((unsigned)f2bf(f0.w) << 16);
  w.z = f2bf(f1.x) | ((unsigned)f2bf(f1.y) << 16);
  w.w = f2bf(f1.z) | ((unsigned)f2bf(f1.w) << 16);
  const int bm = row >> 7, rl = row & 127, kk = c8 >> 3, c8l = c8 & 7;
  char* d = (char*)x_t + (size_t)(bm * 8 + kk) * 16384 + rl * 128 +
            ((c8l * 16) ^ ((rl & 7) << 4));
  *(uint4*)d = w;
}

// ---------------------------------------------------------------------------
// QKV GEMM (m97 structure + T3 2-phase dbuf): M=65536, N=1536, K=512.
// Double-buffered LDS, stage(kk+1) issued BEFORE compute(kk), ONE barrier
// per K-step (its vmcnt drain lands after ~full compute phase -> cheap).
// ---------------------------------------------------------------------------
__global__ __launch_bounds__(256)
void qkv_gemm(const short* __restrict__ x_t, const short* __restrict__ wq_t,
              short* __restrict__ q_g, short* __restrict__ k_g,
              short* __restrict__ vT_g) {
  __shared__ __align__(16) short As[16384];  // 2 x 16KB
  __shared__ __align__(16) short Bs[16384];  // 2 x 16KB
  const int tid = threadIdx.x;
  const int lane = tid & 63;
  const int l15 = lane & 15, l4 = lane >> 4;
  const int wave = tid >> 6;
  const int wm = wave >> 1, wn = wave & 1;
  const int bid = blockIdx.x;  // 6144
  const int wg = (bid & 7) * 768 + (bid >> 3);
  const int bn = wg % 12;
  const int bm = wg / 12;
  char* as_ = (char*)As;
  char* bs_ = (char*)Bs;
  const char* abase = (const char*)x_t + (size_t)bm * 131072;
  const char* bbase = (const char*)wq_t + (size_t)bn * 131072;
  const int soff = tid * 16;

  const f32x4 fz = {0.f, 0.f, 0.f, 0.f};
  f32x4 acc[4][4];
#pragma unroll
  for (int mt = 0; mt < 4; ++mt)
#pragma unroll
    for (int nt = 0; nt < 4; ++nt) acc[mt][nt] = fz;

  // prologue: stage K-step 0 into buffer 0
#pragma unroll
  for (int i = 0; i < 4; ++i) {
    gload_lds16(abase + soff + i * 4096, as_ + soff + i * 4096);
    gload_lds16(bbase + soff + i * 4096, bs_ + soff + i * 4096);
  }
  __syncthreads();  // buffer 0 ready

#pragma unroll 1
  for (int kk = 0; kk < 8; ++kk) {
    const int cb = (kk & 1) * 16384;       // compute buffer byte offset
    if (kk < 7) {                          // issue next stage (async, other buf)
      const int nb2 = ((kk + 1) & 1) * 16384;
      const char* ga = abase + (kk + 1) * 16384 + soff;
      const char* gb = bbase + (kk + 1) * 16384 + soff;
#pragma unroll
      for (int i = 0; i < 4; ++i) {
        gload_lds16(ga + i * 4096, as_ + nb2 + soff + i * 4096);
        gload_lds16(gb + i * 4096, bs_ + nb2 + soff + i * 4096);
      }
    }
#pragma unroll
    for (int ki = 0; ki < 2; ++ki) {
      bf16x8 af[4], bfr[4];
#pragma unroll
      for (int mt = 0; mt < 4; ++mt) {
        const int row = 64 * wm + 16 * mt + l15;
        af[mt] = *(const bf16x8*)(as_ + cb + row * 128 + ((64 * ki + 16 * l4) ^ ((row & 7) << 4)));
      }
#pragma unroll
      for (int nt = 0; nt < 4; ++nt) {
        const int row = 64 * wn + 16 * nt + l15;
        bfr[nt] = *(const bf16x8*)(bs_ + cb + row * 128 + ((64 * ki + 16 * l4) ^ ((row & 7) << 4)));
      }
#pragma unroll
      for (int mt = 0; mt < 4; ++mt)
#pragma unroll
        for (int nt = 0; nt < 4; ++nt)
          acc[mt][nt] = __builtin_amdgcn_mfma_f32_16x16x32_bf16(af[mt], bfr[nt], acc[mt][nt], 0, 0, 0);
    }
    if (kk < 7) __syncthreads();  // drains stage kk+1 (hidden under compute)
  }

  const int three = bn >> 2;  // 0=q 1=k 2=v
  if (three < 2) {
    short* dst = (three == 0) ? q_g : k_g;
#pragma unroll
    for (int mt = 0; mt < 4; ++mt) {
      const int m0 = bm * 128 + 64 * wm + 16 * mt + 4 * l4;
      const int b = m0 >> 6, t0 = m0 & 63;
#pragma unroll
      for (int nt = 0; nt < 4; ++nt) {
        const int n = bn * 128 + 64 * wn + 16 * nt + l15;
        const int h = (n >> 6) & 7, d = n & 63;
        short* p = dst + (size_t)(b * 8 + h) * 4096 + d;
#pragma unroll
        for (int jj = 0; jj < 4; ++jj)
          p[(t0 + jj) * 64] = (short)f2bf(acc[mt][nt][jj]);
      }
    }
  } else {
#pragma unroll
    for (int mt = 0; mt < 4; ++mt) {
      const int m0 = bm * 128 + 64 * wm + 16 * mt + 4 * l4;
      const int b = m0 >> 6, t0 = m0 & 63;
#pragma unroll
      for (int nt = 0; nt < 4; ++nt) {
        const int n = bn * 128 + 64 * wn + 16 * nt + l15;
        const int h = (n >> 6) & 7, d = n & 63;
        uint2 w;
        w.x = cvt_pk_bf16(acc[mt][nt][0], acc[mt][nt][1]);
        w.y = cvt_pk_bf16(acc[mt][nt][2], acc[mt][nt][3]);
        *(uint2*)(vT_g + (size_t)((b * 8 + h) * 64 + d) * 64 + t0) = w;
      }
    }
  }
}

// ---------------------------------------------------------------------------
// attention (round-12 verified, byte-identical): one block per (b,h), 4 waves;
// wave w owns rows [16w,16w+16). d-strip PV, 2 barriers, bf16 P.
// ---------------------------------------------------------------------------
__global__ __launch_bounds__(256, 4)
void attn_kernel(const short* __restrict__ q_g, const short* __restrict__ k_g,
                 const short* __restrict__ vT_g, const short* __restrict__ relk,
                 const short* __restrict__ relvT, short* __restrict__ aout_t) {
  __shared__ __align__(16) short srel_s[64 * 256];  // 32KB swizzled [i][nb]; reused as P
  __shared__ __align__(16) short attn_s[64 * 64];   // 8KB swizzled  [i][j]
  const int tid = threadIdx.x, lane = tid & 63, w = tid >> 6;
  const int l15 = lane & 15, l4 = lane >> 4;
  const int bh = blockIdx.x;
  const short* qb = q_g + (size_t)bh * 4096;
  const short* kb = k_g + (size_t)bh * 4096;
  const short* vb = vT_g + (size_t)bh * 4096;
  char* ss = (char*)srel_s;
  char* as = (char*)attn_s;
  const f32x4 fz = {0.f, 0.f, 0.f, 0.f};

  // ---- Srel^T: D[nb,i] = sum_d relk[nb,d] q[i,d]
  bf16x8 bq[4][2];
#pragma unroll
  for (int nt = 0; nt < 4; ++nt)
#pragma unroll
    for (int kkk = 0; kkk < 2; ++kkk)
      bq[nt][kkk] = *(const bf16x8*)(qb + (16 * nt + l15) * 64 + 32 * kkk + 8 * l4);
#pragma unroll
  for (int mtl = 0; mtl < 4; ++mtl) {
    const int mt = 4 * w + mtl;
    bf16x8 ar0 = *(const bf16x8*)(relk + (16 * mt + l15) * 64 + 8 * l4);
    bf16x8 ar1 = *(const bf16x8*)(relk + (16 * mt + l15) * 64 + 32 + 8 * l4);
#pragma unroll
    for (int nt = 0; nt < 4; ++nt) {
      f32x4 a = fz;
      a = __builtin_amdgcn_mfma_f32_16x16x32_bf16(ar0, bq[nt][0], a, 0, 0, 0);
      a = __builtin_amdgcn_mfma_f32_16x16x32_bf16(ar1, bq[nt][1], a, 0, 0, 0);
      const int i = 16 * nt + l15;
      const int nb0 = 16 * mt + 4 * l4;
      uint2 wv;
      wv.x = cvt_pk_bf16(a[0], a[1]);
      wv.y = cvt_pk_bf16(a[2], a[3]);
      *(uint2*)(ss + i * 512 + ((nb0 * 2) ^ ((i & 7) << 4))) = wv;
    }
  }

  // ---- S^T (own strip): D[j,i] = sum_d k[j,d] q[i,d], i = 16w+l15
  f32x4 sacc[4];
#pragma unroll
  for (int jt = 0; jt < 4; ++jt) {
    sacc[jt] = fz;
    bf16x8 ak0 = *(const bf16x8*)(kb + (16 * jt + l15) * 64 + 8 * l4);
    bf16x8 ak1 = *(const bf16x8*)(kb + (16 * jt + l15) * 64 + 32 + 8 * l4);
    sacc[jt] = __builtin_amdgcn_mfma_f32_16x16x32_bf16(ak0, bq[w][0], sacc[jt], 0, 0, 0);
    sacc[jt] = __builtin_amdgcn_mfma_f32_16x16x32_bf16(ak1, bq[w][1], sacc[jt], 0, 0, 0);
  }
  __syncthreads();  // barrier 1: Srel complete

  // ---- softmax over own rows (4 lanes per row, 16 logits each) ----
  // nb(i,j) = [15*(j>>3)+(j&7)+112] - [15*(i>>3)+(i&7)]; 2nb = 60jt+2rg+off2.
  const int i = 16 * w + l15;
  const int swz = (i & 7) << 4;
  const int ibase = i * 512;
  const int off2 = 2 * (15 * (l4 >> 1) + 4 * (l4 & 1) + 112 - (15 * (i >> 3) + (i & 7)));
  float p[16];
  float mx = -1e30f;
#pragma unroll
  for (int jt = 0; jt < 4; ++jt)
#pragma unroll
    for (int rg = 0; rg < 4; ++rg) {
      const int adr = ibase + (((60 * jt + 2 * rg) + off2) ^ swz);
      const float sr = bf2f(*(const unsigned short*)(ss + adr));
      const float lv = sacc[jt][rg] + sr;
      p[4 * jt + rg] = lv;
      mx = fmaxf(mx, lv);
    }
  mx = fmaxf(mx, __shfl_xor(mx, 16));
  mx = fmaxf(mx, __shfl_xor(mx, 32));
  float sum = 0.f;
#pragma unroll
  for (int q2 = 0; q2 < 16; ++q2) {
    p[q2] = __expf((p[q2] - mx) * 0.125f);
    sum += p[q2];
  }
  sum += __shfl_xor(sum, 16);
  sum += __shfl_xor(sum, 32);
  const float rs = 1.0f / sum;
  unsigned pk[8];
#pragma unroll
  for (int h2 = 0; h2 < 8; ++h2)
    pk[h2] = cvt_pk_bf16(p[2 * h2] * rs, p[2 * h2 + 1] * rs);
  // attn_s[i][j] packed
#pragma unroll
  for (int jt = 0; jt < 4; ++jt) {
    uint2 wv;
    wv.x = pk[2 * jt];
    wv.y = pk[2 * jt + 1];
    *(uint2*)(as + i * 128 + (((16 * jt + 4 * l4) * 2) ^ swz)) = wv;
  }
  {  // zero own P row quarter (gather reads above precede in program order)
    const uint4 uz = {0u, 0u, 0u, 0u};
#pragma unroll
    for (int c = 0; c < 8; ++c)
      *(uint4*)(ss + ibase + ((l4 * 128 + c * 16) ^ swz)) = uz;
  }
#pragma unroll
  for (int jt = 0; jt < 4; ++jt)  // scatter P (injective per row)
#pragma unroll
    for (int rg = 0; rg < 4; ++rg) {
      const int adr = ibase + (((60 * jt + 2 * rg) + off2) ^ swz);
      const int q2 = 4 * jt + rg;
      const unsigned v = pk[q2 >> 1] >> ((q2 & 1) * 16);
      *(unsigned short*)(ss + adr) = (unsigned short)v;
    }
  __syncthreads();  // barrier 2

  // ---- PV: D[d,t] = sum_j vT[d,j]attn[t,j] + sum_nb relvT[d,nb]P[t,nb]
  f32x4 oacc[4];
#pragma unroll
  for (int nt = 0; nt < 4; ++nt) oacc[nt] = fz;
#pragma unroll
  for (int kkk = 0; kkk < 2; ++kkk) {
    bf16x8 av = *(const bf16x8*)(vb + (16 * w + l15) * 64 + 32 * kkk + 8 * l4);
#pragma unroll
    for (int nt = 0; nt < 4; ++nt) {
      const int t = 16 * nt + l15;
      bf16x8 bp = *(const bf16x8*)(as + t * 128 + (((32 * kkk + 8 * l4) * 2) ^ ((t & 7) << 4)));
      oacc[nt] = __builtin_amdgcn_mfma_f32_16x16x32_bf16(av, bp, oacc[nt], 0, 0, 0);
    }
  }
#pragma unroll
  for (int kkk = 0; kkk < 8; ++kkk) {
    bf16x8 arv = *(const bf16x8*)(relvT + (16 * w + l15) * 256 + 32 * kkk + 8 * l4);
#pragma unroll
    for (int nt = 0; nt < 4; ++nt) {
      const int t = 16 * nt + l15;
      bf16x8 bp = *(const bf16x8*)(ss + t * 512 + (((32 * kkk + 8 * l4) * 2) ^ ((t & 7) << 4)));
      oacc[nt] = __builtin_amdgcn_mfma_f32_16x16x32_bf16(arv, bp, oacc[nt], 0, 0, 0);
    }
  }
  // epilogue: write into proj tile image. row m = b*64+t; tile bm=m>>7,
  // kk = h; in-tile r = (b&1)*64 + t, c = d.
  const int b = bh >> 3, h = bh & 7;
  char* abase = (char*)aout_t + (size_t)((b >> 1) * 8 + h) * 16384;
  const int rbase = (b & 1) * 64;
#pragma unroll
  for (int nt = 0; nt < 4; ++nt) {
    const int t = 16 * nt + l15;
    const int r = rbase + t;
    const int d0 = 16 * w + 4 * l4;
    uint2 wv;
    wv.x = cvt_pk_bf16(oacc[nt][0], oacc[nt][1]);
    wv.y = cvt_pk_bf16(oacc[nt][2], oacc[nt][3]);
    *(uint2*)(abase + r * 128 + ((d0 * 2) ^ ((r & 7) << 4))) = wv;
  }
}

// ---------------------------------------------------------------------------
// proj (m97 structure + T3 2-phase dbuf): out = aout @ wproj^T + b_proj.
// ---------------------------------------------------------------------------
__global__ __launch_bounds__(256)
void proj_kernel(const short* __restrict__ a_t, const short* __restrict__ wp_t,
                 const float* __restrict__ bproj, float* __restrict__ out) {
  __shared__ __align__(16) short As[16384];  // 2 x 16KB
  __shared__ __align__(16) short Bs[16384];  // 2 x 16KB
  const int tid = threadIdx.x;
  const int lane = tid & 63;
  const int wave = tid >> 6;
  const int wm = wave >> 1, wn = wave & 1;
  const int l15 = lane & 15, l4 = lane >> 4;
  const int bid = blockIdx.x;  // 2048
  const int wg = (bid & 7) * 256 + (bid >> 3);
  const int bn = wg & 3;
  const int bm = wg >> 2;
  char* as_ = (char*)As;
  char* bs_ = (char*)Bs;
  const char* abase = (const char*)a_t + (size_t)bm * 131072;
  const char* bbase = (const char*)wp_t + (size_t)bn * 131072;
  const int soff = tid * 16;

  const f32x4 fz = {0.f, 0.f, 0.f, 0.f};
  f32x4 acc[4][4];
#pragma unroll
  for (int mt = 0; mt < 4; ++mt)
#pragma unroll
    for (int nt = 0; nt < 4; ++nt) acc[mt][nt] = fz;

  // prologue: stage K-step 0 into buffer 0
#pragma unroll
  for (int i = 0; i < 4; ++i) {
    gload_lds16(abase + soff + i * 4096, as_ + soff + i * 4096);
    gload_lds16(bbase + soff + i * 4096, bs_ + soff + i * 4096);
  }
  __syncthreads();

#pragma unroll 1
  for (int kk = 0; kk < 8; ++kk) {
    const int cb = (kk & 1) * 16384;
    if (kk < 7) {
      const int nb2 = ((kk + 1) & 1) * 16384;
      const char* ga = abase + (kk + 1) * 16384 + soff;
      const char* gb = bbase + (kk + 1) * 16384 + soff;
#pragma unroll
      for (int i = 0; i < 4; ++i) {
        gload_lds16(ga + i * 4096, as_ + nb2 + soff + i * 4096);
        gload_lds16(gb + i * 4096, bs_ + nb2 + soff + i * 4096);
      }
    }
#pragma unroll
    for (int ki = 0; ki < 2; ++ki) {
      bf16x8 af[4], bq[4];
#pragma unroll
      for (int mt = 0; mt < 4; ++mt) {
        const int row = 64 * wm + 16 * mt + l15;
        af[mt] = *(const bf16x8*)(as_ + cb + row * 128 + ((64 * ki + 16 * l4) ^ ((row & 7) << 4)));
      }
#pragma unroll
      for (int nt = 0; nt < 4; ++nt) {
        const int row = 64 * wn + 16 * nt + l15;
        bq[nt] = *(const bf16x8*)(bs_ + cb + row * 128 + ((64 * ki + 16 * l4) ^ ((row & 7) << 4)));
      }
#pragma unroll
      for (int mt = 0; mt < 4; ++mt)
#pragma unroll
        for (int nt = 0; nt < 4; ++nt)
          acc[mt][nt] = __builtin_amdgcn_mfma_f32_16x16x32_bf16(af[mt], bq[nt], acc[mt][nt], 0, 0, 0);
    }
    if (kk < 7) __syncthreads();
  }
#pragma unroll
  for (int nt = 0; nt < 4; ++nt) {
    const int col = bn * 128 + 64 * wn + 16 * nt + l15;
    const float bias = bproj[col];
#pragma unroll
    for (int mt = 0; mt < 4; ++mt) {
      const int r0 = bm * 128 + 64 * wm + 16 * mt + 4 * l4;
#pragma unroll
      for (int jj = 0; jj < 4; ++jj)
        out[(size_t)(r0 + jj) * 512 + col] = acc[mt][nt][jj] + bias;
    }
  }
}

// ---------------------------------------------------------------------------
extern "C" void kernel_launch(void* const* d_in, const int* in_sizes, int n_in,
                              void* d_out, int out_size, void* d_ws, size_t ws_size,
                              hipStream_t stream) {
  const float* x = (const float*)d_in[0];
  const float* wqkv = (const float*)d_in[1];
  const float* wproj = (const float*)d_in[2];
  const float* bproj = (const float*)d_in[3];
  const float* relk = (const float*)d_in[4];
  const float* relv = (const float*)d_in[5];
  float* out = (float*)d_out;

  char* ws = (char*)d_ws;
  const size_t MB = 1024 * 1024;
  // region A (64MB): x_t during qkv_gemm, then aout_t from attn onward
  short* xa_t = (short*)ws;
  short* vT_g = (short*)(ws + 64 * MB);                 // 64MB
  short* wq_t = (short*)(ws + 128 * MB);                // 1.5MB
  short* wp_t = (short*)(ws + 128 * MB + 1572864);      // 0.5MB
  short* relk_b = (short*)(ws + 128 * MB + 2097152);    // 32KB
  short* relvT_b = (short*)(ws + 128 * MB + 2129920);   // 32KB
  short* q_gg = (short*)d_out;                          // parked in d_out
  short* k_gg = (short*)((char*)d_out + 64 * MB);       // until proj overwrites

  prep_kernel<<<dim3(528), dim3(256), 0, stream>>>(wqkv, wproj, relk, relv, wq_t,
                                                   wp_t, relk_b, relvT_b);
  xconv_kernel<<<dim3(16384), dim3(256), 0, stream>>>(x, xa_t);
  qkv_gemm<<<dim3(6144), dim3(256), 0, stream>>>(xa_t, wq_t, q_gg, k_gg, vT_g);
  attn_kernel<<<dim3(8192), dim3(256), 0, stream>>>(q_gg, k_gg, vT_g, relk_b,
                                                    relvT_b, xa_t);
  proj_kernel<<<dim3(2048), dim3(256), 0, stream>>>(xa_t, wp_t, bproj, out);
}